// Round 2
// baseline (947.686 us; speedup 1.0000x reference)
//
#include <hip/hip_runtime.h>
#include <stdint.h>

// GMHCA: B=4, Lq=1024, Lkv=2048, NH=16, D=64.
// I/O is fp32 (per reference); internal compute bf16 MFMA.
// d_out (fp32) = [ out 4*1024*1024 | attn 64*1024*2048 ].

typedef unsigned short ushort_t;
typedef __bf16 bf16x8 __attribute__((ext_vector_type(8)));
typedef float  f32x4  __attribute__((ext_vector_type(4)));
typedef ushort_t u16x8 __attribute__((ext_vector_type(8)));

__device__ __forceinline__ float bf2f(ushort_t h) {
  union { unsigned int u; float f; } c; c.u = ((unsigned int)h) << 16; return c.f;
}
__device__ __forceinline__ ushort_t f2bf(float f) {
  union { float f; unsigned int u; } c; c.f = f;
  unsigned int u = c.u;
  return (ushort_t)((u + 0x7FFFu + ((u >> 16) & 1u)) >> 16);  // RNE
}

// ---------------------------------------------------------------------------
// Weight convert+transpose: out_bf16[c*ldo + r] = (bf16) in_f32[r*ldi + c]
// ---------------------------------------------------------------------------
__global__ void wconv_t(const float* __restrict__ in, ushort_t* __restrict__ out,
                        int ldi, int ldo) {
  __shared__ ushort_t t[32][33];
  const int r0 = blockIdx.y * 32, c0 = blockIdx.x * 32;
  const int tx = threadIdx.x & 31, ty = threadIdx.x >> 5;
#pragma unroll
  for (int i = 0; i < 4; i++) {
    int r = ty + i * 8;
    t[r][tx] = f2bf(in[(long)(r0 + r) * ldi + c0 + tx]);
  }
  __syncthreads();
#pragma unroll
  for (int i = 0; i < 4; i++) {
    int c = ty + i * 8;
    out[(long)(c0 + c) * ldo + r0 + tx] = t[tx][c];
  }
}

// bf16 transpose (for V^T)
__global__ void transpose_bf16(const ushort_t* __restrict__ in,
                               ushort_t* __restrict__ out, int ldi, int ldo) {
  __shared__ ushort_t t[32][33];
  const int r0 = blockIdx.y * 32, c0 = blockIdx.x * 32;
  const int tx = threadIdx.x & 31, ty = threadIdx.x >> 5;
#pragma unroll
  for (int i = 0; i < 4; i++) {
    int r = ty + i * 8;
    t[r][tx] = in[(long)(r0 + r) * ldi + c0 + tx];
  }
  __syncthreads();
#pragma unroll
  for (int i = 0; i < 4; i++) {
    int c = ty + i * 8;
    out[(long)(c0 + c) * ldo + r0 + tx] = t[tx][c];
  }
}

// ---------------------------------------------------------------------------
// C[M,N] = A[M,K] @ Bt[N,K]^T (+bias). A fp32 or bf16 (AF32), C fp32 or bf16
// (CF32). Bt always bf16. 128x128 tile, BK=64, 4 waves, 16x16x32 bf16 MFMA.
// ---------------------------------------------------------------------------
#define GLDT 72  // 64 + 8 pad (16B-aligned rows, 2-way bank alias = free)

template <bool AF32, bool CF32>
__global__ __launch_bounds__(256, 2) void gemm_bt(
    const void* __restrict__ Ap, const ushort_t* __restrict__ Bt,
    void* __restrict__ Cp, const float* __restrict__ bias,
    int K, int lda, int ldb, int ldc) {
  __shared__ ushort_t As[128 * GLDT];
  __shared__ ushort_t Bs[128 * GLDT];
  const int tid  = threadIdx.x;
  const int wave = tid >> 6, lane = tid & 63;
  const int quad = lane >> 4, l15 = lane & 15;
  const int wr = wave >> 1, wc = wave & 1;
  const long m0 = (long)blockIdx.x * 128;
  const long n0 = (long)blockIdx.y * 128;
  const int ar = tid >> 3;       // 0..31
  const int ac = (tid & 7) * 8;  // 0..56

  f32x4 acc[4][4];
#pragma unroll
  for (int i = 0; i < 4; i++)
#pragma unroll
    for (int j = 0; j < 4; j++) acc[i][j] = (f32x4)0.0f;

  for (int k0 = 0; k0 < K; k0 += 64) {
    __syncthreads();
#pragma unroll
    for (int p = 0; p < 4; p++) {
      int row = p * 32 + ar;
      if (AF32) {
        const float* A = (const float*)Ap;
        f32x4 x0 = *(const f32x4*)(&A[(m0 + row) * lda + k0 + ac]);
        f32x4 x1 = *(const f32x4*)(&A[(m0 + row) * lda + k0 + ac + 4]);
        u16x8 v;
#pragma unroll
        for (int e = 0; e < 4; e++) { v[e] = f2bf(x0[e]); v[4 + e] = f2bf(x1[e]); }
        *(u16x8*)(&As[row * GLDT + ac]) = v;
      } else {
        const ushort_t* A = (const ushort_t*)Ap;
        *(u16x8*)(&As[row * GLDT + ac]) =
            *(const u16x8*)(&A[(m0 + row) * lda + k0 + ac]);
      }
      *(u16x8*)(&Bs[row * GLDT + ac]) =
          *(const u16x8*)(&Bt[(n0 + row) * ldb + k0 + ac]);
    }
    __syncthreads();
#pragma unroll
    for (int ks = 0; ks < 64; ks += 32) {
      bf16x8 af[4], bfr[4];
#pragma unroll
      for (int i = 0; i < 4; i++)
        af[i] = *(const bf16x8*)(&As[(wr * 64 + i * 16 + l15) * GLDT + ks + quad * 8]);
#pragma unroll
      for (int j = 0; j < 4; j++)
        bfr[j] = *(const bf16x8*)(&Bs[(wc * 64 + j * 16 + l15) * GLDT + ks + quad * 8]);
#pragma unroll
      for (int i = 0; i < 4; i++)
#pragma unroll
        for (int j = 0; j < 4; j++)
          acc[i][j] = __builtin_amdgcn_mfma_f32_16x16x32_bf16(af[i], bfr[j], acc[i][j], 0, 0, 0);
    }
  }
  // C/D layout: col = lane&15, row = quad*4 + reg (m89/m91-verified)
#pragma unroll
  for (int i = 0; i < 4; i++) {
    long row = m0 + wr * 64 + i * 16 + quad * 4;
#pragma unroll
    for (int j = 0; j < 4; j++) {
      long col = n0 + wc * 64 + j * 16 + l15;
      float bv = bias ? bias[col] : 0.0f;
#pragma unroll
      for (int r = 0; r < 4; r++) {
        float v = acc[i][j][r] + bv;
        if (CF32) ((float*)Cp)[(row + r) * ldc + col] = v;
        else      ((ushort_t*)Cp)[(row + r) * ldc + col] = f2bf(v);
      }
    }
  }
}

// ---------------------------------------------------------------------------
// Fused attention. Block = (b*16+h, 64 q rows). Two-pass online softmax in
// exp2 domain; P written fp32 to d_out via LDS (coalesced); PV fused.
// ---------------------------------------------------------------------------
#define LQK 72    // 64 + 8
#define LPJ 136   // 128 + 8

__global__ __launch_bounds__(256, 2) void attn_kernel(
    const ushort_t* __restrict__ qb,  // [B*1024, 1024] bf16
    const ushort_t* __restrict__ kb,  // [B*2048, 1024] bf16 (K proj)
    const ushort_t* __restrict__ vt,  // [B*16*64, 2048] bf16 (V^T)
    float* __restrict__ pout,         // [64, 1024, 2048] fp32
    ushort_t* __restrict__ ao) {      // [B*1024, 1024] bf16
  __shared__ ushort_t Qs[64 * LQK];
  __shared__ ushort_t Ks[128 * LQK];
  __shared__ ushort_t Vs[64 * LPJ];
  __shared__ ushort_t Ps[64 * LPJ];

  const int tid  = threadIdx.x;
  const int wave = tid >> 6, lane = tid & 63;
  const int quad = lane >> 4, l15 = lane & 15;
  const int bn = blockIdx.x;  // 0..63
  const int b = bn >> 4, h = bn & 15;
  const int q0 = blockIdx.y * 64;
  const float SL2E = 0.125f * 1.44269504088896340736f;  // scale * log2(e)

  {  // stage Q tile [64 x 64]
    int r = tid >> 3, c = (tid & 7) * 8;
#pragma unroll
    for (int p = 0; p < 2; p++) {
      int row = p * 32 + r;
      *(u16x8*)(&Qs[row * LQK + c]) =
          *(const u16x8*)(&qb[((long)(b * 1024 + q0 + row)) * 1024 + h * 64 + c]);
    }
  }
  __syncthreads();
  bf16x8 aq0 = *(const bf16x8*)(&Qs[(wave * 16 + l15) * LQK + quad * 8]);
  bf16x8 aq1 = *(const bf16x8*)(&Qs[(wave * 16 + l15) * LQK + 32 + quad * 8]);

  float m[4], l[4];
#pragma unroll
  for (int r = 0; r < 4; r++) { m[r] = -1e30f; l[r] = 0.0f; }

  // ---- pass 1: row max + denom ----
  for (int t0 = 0; t0 < 2048; t0 += 128) {
    __syncthreads();
    {
      int r = tid >> 3, c = (tid & 7) * 8;
#pragma unroll
      for (int p = 0; p < 4; p++) {
        int row = p * 32 + r;
        *(u16x8*)(&Ks[row * LQK + c]) =
            *(const u16x8*)(&kb[((long)(b * 2048 + t0 + row)) * 1024 + h * 64 + c]);
      }
    }
    __syncthreads();
    float u[8][4];
#pragma unroll
    for (int ni = 0; ni < 8; ni++) {
      bf16x8 b0 = *(const bf16x8*)(&Ks[(ni * 16 + l15) * LQK + quad * 8]);
      bf16x8 b1 = *(const bf16x8*)(&Ks[(ni * 16 + l15) * LQK + 32 + quad * 8]);
      f32x4 s = (f32x4)0.0f;
      s = __builtin_amdgcn_mfma_f32_16x16x32_bf16(aq0, b0, s, 0, 0, 0);
      s = __builtin_amdgcn_mfma_f32_16x16x32_bf16(aq1, b1, s, 0, 0, 0);
#pragma unroll
      for (int r = 0; r < 4; r++) u[ni][r] = s[r] * SL2E;
    }
#pragma unroll
    for (int r = 0; r < 4; r++) {
      float tm = u[0][r];
#pragma unroll
      for (int ni = 1; ni < 8; ni++) tm = fmaxf(tm, u[ni][r]);
      tm = fmaxf(tm, __shfl_xor(tm, 1));
      tm = fmaxf(tm, __shfl_xor(tm, 2));
      tm = fmaxf(tm, __shfl_xor(tm, 4));
      tm = fmaxf(tm, __shfl_xor(tm, 8));
      float mn = fmaxf(m[r], tm);
      float ts = 0.0f;
#pragma unroll
      for (int ni = 0; ni < 8; ni++) ts += __builtin_amdgcn_exp2f(u[ni][r] - mn);
      ts += __shfl_xor(ts, 1);
      ts += __shfl_xor(ts, 2);
      ts += __shfl_xor(ts, 4);
      ts += __shfl_xor(ts, 8);
      l[r] = l[r] * __builtin_amdgcn_exp2f(m[r] - mn) + ts;
      m[r] = mn;
    }
  }

  float rl[4];
#pragma unroll
  for (int r = 0; r < 4; r++) rl[r] = 1.0f / l[r];

  f32x4 o[4];
#pragma unroll
  for (int d = 0; d < 4; d++) o[d] = (f32x4)0.0f;

  // ---- pass 2: recompute S, write exact P (fp32), fused PV ----
  for (int t0 = 0; t0 < 2048; t0 += 128) {
    __syncthreads();
    {
      int r = tid >> 3, c = (tid & 7) * 8;
#pragma unroll
      for (int p = 0; p < 4; p++) {
        int row = p * 32 + r;
        *(u16x8*)(&Ks[row * LQK + c]) =
            *(const u16x8*)(&kb[((long)(b * 2048 + t0 + row)) * 1024 + h * 64 + c]);
      }
      int r2 = tid >> 4, c2 = (tid & 15) * 8;
#pragma unroll
      for (int p = 0; p < 4; p++) {
        int row = p * 16 + r2;
        *(u16x8*)(&Vs[row * LPJ + c2]) =
            *(const u16x8*)(&vt[((long)(bn * 64 + row)) * 2048 + t0 + c2]);
      }
    }
    __syncthreads();
#pragma unroll
    for (int ni = 0; ni < 8; ni++) {
      bf16x8 b0 = *(const bf16x8*)(&Ks[(ni * 16 + l15) * LQK + quad * 8]);
      bf16x8 b1 = *(const bf16x8*)(&Ks[(ni * 16 + l15) * LQK + 32 + quad * 8]);
      f32x4 s = (f32x4)0.0f;
      s = __builtin_amdgcn_mfma_f32_16x16x32_bf16(aq0, b0, s, 0, 0, 0);
      s = __builtin_amdgcn_mfma_f32_16x16x32_bf16(aq1, b1, s, 0, 0, 0);
#pragma unroll
      for (int r = 0; r < 4; r++) {
        float pv = __builtin_amdgcn_exp2f(s[r] * SL2E - m[r]) * rl[r];
        Ps[(wave * 16 + quad * 4 + r) * LPJ + ni * 16 + l15] = f2bf(pv);
      }
    }
    __syncthreads();
    // P write-out fp32 (LDS bf16 -> cvt -> 2x float4 per lane, coalesced)
    {
      int r = tid >> 4, c = (tid & 15) * 8;
#pragma unroll
      for (int p = 0; p < 4; p++) {
        int row = p * 16 + r;
        const ushort_t* src = &Ps[row * LPJ + c];
        float* dst = &pout[((long)bn * 1024 + q0 + row) * 2048 + t0 + c];
        f32x4 lo, hi;
#pragma unroll
        for (int e = 0; e < 4; e++) { lo[e] = bf2f(src[e]); hi[e] = bf2f(src[4 + e]); }
        *(f32x4*)dst = lo;
        *(f32x4*)(dst + 4) = hi;
      }
    }
    // fused PV: O[16q x 64d] per wave
#pragma unroll
    for (int js = 0; js < 128; js += 32) {
      bf16x8 ap = *(const bf16x8*)(&Ps[(wave * 16 + l15) * LPJ + js + quad * 8]);
#pragma unroll
      for (int d = 0; d < 4; d++) {
        bf16x8 bv = *(const bf16x8*)(&Vs[(d * 16 + l15) * LPJ + js + quad * 8]);
        o[d] = __builtin_amdgcn_mfma_f32_16x16x32_bf16(ap, bv, o[d], 0, 0, 0);
      }
    }
  }
#pragma unroll
  for (int d = 0; d < 4; d++) {
#pragma unroll
    for (int r = 0; r < 4; r++) {
      int row = q0 + wave * 16 + quad * 4 + r;
      int col = h * 64 + d * 16 + l15;
      ao[((long)(b * 1024 + row)) * 1024 + col] = f2bf(o[d][r]);
    }
  }
}

// ---------------------------------------------------------------------------
extern "C" void kernel_launch(void* const* d_in, const int* in_sizes, int n_in,
                              void* d_out, int out_size, void* d_ws, size_t ws_size,
                              hipStream_t stream) {
  (void)in_sizes; (void)n_in; (void)out_size; (void)ws_size;
  const float* query   = (const float*)d_in[0];  // [4,1024,1024]
  const float* context = (const float*)d_in[1];  // [4,2048,1024]
  const float* Wq      = (const float*)d_in[2];  // [1024,1024]
  const float* Wkv     = (const float*)d_in[3];  // [1024,2048]
  const float* Wo      = (const float*)d_in[4];  // [1024,1024]
  const float* bo      = (const float*)d_in[5];  // [1024]
  float* out = (float*)d_out;

  // ws layout (64 MB total), manual lifetimes:
  char* ws = (char*)d_ws;
  ushort_t* WoT  = (ushort_t*)(ws);                 // 2 MB  [-> final gemm]
  ushort_t* WqT  = (ushort_t*)(ws + (2ll  << 20));  // 2 MB  [-> q gemm]
  ushort_t* WkvT = (ushort_t*)(ws + (4ll  << 20));  // 4 MB  [-> k/v gemm]
  ushort_t* qbuf = (ushort_t*)(ws + (8ll  << 20));  // 8 MB  [-> attn]
  ushort_t* kbuf = (ushort_t*)(ws + (16ll << 20));  // 16 MB [-> attn]
  ushort_t* vbuf = (ushort_t*)(ws + (32ll << 20));  // 16 MB [-> vt transpose]
  ushort_t* vt   = (ushort_t*)(ws + (48ll << 20));  // 16 MB [-> attn]
  ushort_t* ao   = vbuf;  // 8 MB, aliases vbuf (dead after vt is built)

  // weight convert+transpose -> bf16 [out,in]
  wconv_t<<<dim3(32, 32), 256, 0, stream>>>(Wq, WqT, 1024, 1024);
  wconv_t<<<dim3(64, 32), 256, 0, stream>>>(Wkv, WkvT, 2048, 1024);
  wconv_t<<<dim3(32, 32), 256, 0, stream>>>(Wo, WoT, 1024, 1024);

  // projections (A fp32 -> C bf16)
  gemm_bt<true, false><<<dim3(32, 8), 256, 0, stream>>>(
      query, WqT, qbuf, nullptr, 1024, 1024, 1024, 1024);
  gemm_bt<true, false><<<dim3(64, 8), 256, 0, stream>>>(
      context, WkvT, kbuf, nullptr, 1024, 1024, 1024, 1024);
  gemm_bt<true, false><<<dim3(64, 8), 256, 0, stream>>>(
      context, WkvT + 1024ll * 1024, vbuf, nullptr, 1024, 1024, 1024, 1024);

  // V^T per batch: vt[(b*16+h)*64+d][j] = vbuf[(b*2048+j)][h*64+d]
  for (int b = 0; b < 4; b++)
    transpose_bf16<<<dim3(32, 64), 256, 0, stream>>>(
        vbuf + (long)b * 2048 * 1024, vt + (long)b * 1024 * 2048, 1024, 2048);

  // fused attention: P (fp32) -> d_out[4M..], head outputs -> ao
  attn_kernel<<<dim3(64, 16), 256, 0, stream>>>(qbuf, kbuf, vt, out + 4194304, ao);

  // output projection + bias -> d_out[0..4M)
  gemm_bt<false, true><<<dim3(32, 8), 256, 0, stream>>>(
      ao, WoT, out, bo, 1024, 1024, 1024, 1024);
}